// Round 5
// baseline (586.840 us; speedup 1.0000x reference)
//
#include <hip/hip_runtime.h>
#include <hip/hip_fp16.h>
#include <math.h>

// RotationLayer: out = x + scatter_add over edges of rotated neighbor vectors.
//   t_u = R(+phase) @ x[u]  accumulated into out[v]
//   t_v = R(-phase) @ x[v]  accumulated into out[u]
//
// Round 5: partition was latency/barrier-bound (32% occupancy, 21 barriers).
//  - LDS diet: 45 KB -> 38.1 KB => 4 blocks/CU (16 waves).
//  - wave-shuffle scan (2 buckets/thread + __shfl_up) => 6 barriers/block.
//  - nontemporal loads for edges/phases + nontemporal record stores: keeps
//    the 4 MB half2 x-table L2-resident, cuts record RFO.
//  - accumulate: 16 B nontemporal record loads, native int LDS atomics.

#define NODE_SHIFT   11
#define BUCKET_NODES 2048
#define MAX_NB       512
#define PART_BLOCK   256
#define EPT          8                       // edges per thread (in registers)
#define EPB          (PART_BLOCK * EPT)      // 2048 edges per block
#define RPB          (2 * EPB)               // 4096 records per block

#define ACC_BLOCK    512
#define FIX_SCALE    65536.0f
#define INV_FIX      (1.0f / 65536.0f)

typedef unsigned int uint;
typedef unsigned long long ull;
typedef ull ull2_t __attribute__((ext_vector_type(2)));

static __device__ __forceinline__ uint pack_half2(float a, float b) {
    __half2 h = __floats2half2_rn(a, b);
    union { __half2 h2; uint u; } cvt; cvt.h2 = h; return cvt.u;
}

__global__ __launch_bounds__(256) void rot_make_xh(const float2* __restrict__ x2,
                                                   __half2* __restrict__ xh, int n) {
    int i = blockIdx.x * blockDim.x + threadIdx.x;
    if (i < n) {
        float2 v = x2[i];
        xh[i] = __floats2half2_rn(v.x, v.y);   // regular store: want it cached
    }
}

__global__ __launch_bounds__(256) void rot_zero_cursors(uint* __restrict__ cursors, int nb) {
    int i = blockIdx.x * blockDim.x + threadIdx.x;
    if (i < nb) cursors[i] = 0u;
}

__global__ __launch_bounds__(PART_BLOCK) void rot_partition(
    const __half2* __restrict__ xh,
    const float*  __restrict__ phases,
    const int2*   __restrict__ edges,
    uint*  __restrict__ cursors,
    uint2* __restrict__ records,
    int e_begin, int e_end, int cap, int nbp)
{
    __shared__ uint2 s_rec[RPB];     // 32 KB sorted record staging
    __shared__ uint  s_cnt[MAX_NB];  // 2 KB histogram
    __shared__ uint  s_cur[MAX_NB];  // 2 KB placement cursors (init = local excl)
    __shared__ int   s_diff[MAX_NB]; // 2 KB global_base - local_excl
    __shared__ uint  s_wsum[8];      // wave scan partials

    const int tid  = threadIdx.x;
    const int lane = tid & 63;
    const int wv   = tid >> 6;
    const int block_e0 = e_begin + blockIdx.x * EPB;

    // ---- 1. Stream edges+phases into registers (nontemporal, coalesced) ----
    int2  ed[EPT];
    float ph[EPT];
    __half2 hu[EPT], hv[EPT];
    #pragma unroll
    for (int i = 0; i < EPT; ++i) {
        int e = block_e0 + i * PART_BLOCK + tid;
        if (e < e_end) {
            ull ep = __builtin_nontemporal_load((const ull*)&edges[e]);
            ed[i].x = (int)(ep & 0xFFFFFFFFull);
            ed[i].y = (int)(ep >> 32);
            ph[i]   = __builtin_nontemporal_load(&phases[e]);
        } else { ed[i] = make_int2(0, 0); ph[i] = 0.f; }
    }
    // ---- 2. Issue all gathers now; latency hides behind histogram+scan ----
    #pragma unroll
    for (int i = 0; i < EPT; ++i) {
        hu[i] = xh[ed[i].x];
        hv[i] = xh[ed[i].y];
    }

    // ---- 3. Histogram ----
    #pragma unroll
    for (int k = 0; k < MAX_NB / PART_BLOCK; ++k) s_cnt[tid + k * PART_BLOCK] = 0u;
    __syncthreads();
    #pragma unroll
    for (int i = 0; i < EPT; ++i) {
        int e = block_e0 + i * PART_BLOCK + tid;
        if (e < e_end) {
            atomicAdd(&s_cnt[(uint)ed[i].y >> NODE_SHIFT], 1u);
            atomicAdd(&s_cnt[(uint)ed[i].x >> NODE_SHIFT], 1u);
        }
    }
    __syncthreads();

    // ---- 4. Exclusive scan: 2 buckets/thread, wave shuffles ----
    const int b0 = 2 * tid, b1 = 2 * tid + 1;
    uint c0 = (b0 < nbp) ? s_cnt[b0] : 0u;
    uint c1 = (b1 < nbp) ? s_cnt[b1] : 0u;
    uint local = c0 + c1;
    uint incl = local;
    #pragma unroll
    for (int off = 1; off < 64; off <<= 1) {
        uint n = __shfl_up(incl, off, 64);
        if (lane >= off) incl += n;
    }
    if (lane == 63) s_wsum[wv] = incl;
    __syncthreads();
    uint prefix = 0;
    #pragma unroll
    for (int w = 0; w < 4; ++w) prefix += (w < wv) ? s_wsum[w] : 0u;
    uint excl0 = prefix + incl - local;
    uint excl1 = excl0 + c0;
    // ---- 5. Local cursors + global reservation (1 atomic per bucket) ----
    if (b0 < nbp) {
        uint base = c0 ? atomicAdd(&cursors[b0], c0) : 0u;
        s_cur[b0]  = excl0;
        s_diff[b0] = (int)base - (int)excl0;
    }
    if (b1 < nbp) {
        uint base = c1 ? atomicAdd(&cursors[b1], c1) : 0u;
        s_cur[b1]  = excl1;
        s_diff[b1] = (int)base - (int)excl1;
    }
    __syncthreads();

    // ---- 6. Compute rotations, place records sorted-by-bucket in LDS ----
    #pragma unroll
    for (int i = 0; i < EPT; ++i) {
        int e = block_e0 + i * PART_BLOCK + tid;
        if (e < e_end) {
            int u = ed[i].x, v = ed[i].y;
            float s, c;
            __sincosf(ph[i], &s, &c);
            float2 fu = __half22float2(hu[i]);
            float2 fv = __half22float2(hv[i]);
            float tux = fu.x * c - fu.y * s;   // -> out[v]
            float tuy = fu.x * s + fu.y * c;
            float tvx = fv.x * c + fv.y * s;   // -> out[u]
            float tvy = fv.y * c - fv.x * s;
            {
                uint b = (uint)v >> NODE_SHIFT;
                uint slot = atomicAdd(&s_cur[b], 1u);
                s_rec[slot] = make_uint2((b << 16) | ((uint)v & (BUCKET_NODES - 1)),
                                         pack_half2(tux, tuy));
            }
            {
                uint b = (uint)u >> NODE_SHIFT;
                uint slot = atomicAdd(&s_cur[b], 1u);
                s_rec[slot] = make_uint2((b << 16) | ((uint)u & (BUCKET_NODES - 1)),
                                         pack_half2(tvx, tvy));
            }
        }
    }
    __syncthreads();

    // ---- 7. Coalesced flush (nontemporal 8 B stores) ----
    int valid_edges = e_end - block_e0;
    if (valid_edges > EPB) valid_edges = EPB;
    int total = 2 * valid_edges;
    for (int s = tid; s < total; s += PART_BLOCK) {
        uint2 r = s_rec[s];
        uint b = r.x >> 16;
        int g = s + s_diff[b];
        if ((uint)g < (uint)cap) {
            ull packed = (ull)r.x | ((ull)r.y << 32);
            __builtin_nontemporal_store(packed, (ull*)&records[(size_t)b * cap + g]);
        }
    }
}

static __device__ __forceinline__ void acc_record(int* accX, int* accY, ull r) {
    uint key = (uint)(r & 0xFFFFFFFFull);
    uint pay = (uint)(r >> 32);
    union { uint u; __half2 h; } cvt; cvt.u = pay;
    float2 f = __half22float2(cvt.h);
    uint node = key & (BUCKET_NODES - 1);
    atomicAdd(&accX[node], __float2int_rn(f.x * FIX_SCALE));
    atomicAdd(&accY[node], __float2int_rn(f.y * FIX_SCALE));
}

__global__ __launch_bounds__(ACC_BLOCK) void rot_accumulate(
    const float2* __restrict__ x2,
    const uint*   __restrict__ cursors,
    const uint2*  __restrict__ records,
    float2* __restrict__ out2,
    int cap, int n_nodes, int first_chunk)
{
    __shared__ int accX[BUCKET_NODES];
    __shared__ int accY[BUCKET_NODES];
    for (int i = threadIdx.x; i < BUCKET_NODES; i += ACC_BLOCK) {
        accX[i] = 0; accY[i] = 0;
    }
    __syncthreads();

    const int b = blockIdx.x;
    uint cnt = cursors[b];
    if (cnt > (uint)cap) cnt = (uint)cap;
    const uint2* rec = records + (size_t)b * cap;

    // 16 B nontemporal loads: 2 records per iteration per thread
    const ull2_t* rec16 = (const ull2_t*)rec;
    uint n2 = cnt >> 1;
    for (uint i = threadIdx.x; i < n2; i += ACC_BLOCK) {
        ull2_t r = __builtin_nontemporal_load(&rec16[i]);
        acc_record(accX, accY, r.x);
        acc_record(accX, accY, r.y);
    }
    if ((cnt & 1u) && threadIdx.x == 0) {
        ull r = __builtin_nontemporal_load((const ull*)&rec[cnt - 1]);
        acc_record(accX, accY, r);
    }
    __syncthreads();

    const int node0 = b << NODE_SHIFT;
    for (int i = threadIdx.x; i < BUCKET_NODES; i += ACC_BLOCK) {
        int node = node0 + i;
        if (node < n_nodes) {
            float ax = (float)accX[i] * INV_FIX;
            float ay = (float)accY[i] * INV_FIX;
            float2 base = first_chunk ? x2[node] : out2[node];
            out2[node] = make_float2(base.x + ax, base.y + ay);
        }
    }
}

// ---------------- fallback (atomic path, used only if ws too small) ----------

__global__ __launch_bounds__(256) void rot_init_out(const float* __restrict__ x,
                                                    float* __restrict__ out, int n) {
    int i = blockIdx.x * blockDim.x + threadIdx.x;
    if (i < n) out[i] = x[i];
}

__global__ __launch_bounds__(256) void rot_edge_atomic(
    const float2* __restrict__ x2, const float* __restrict__ phases,
    const int2* __restrict__ edges, float* __restrict__ out, int n_edges)
{
    int e = blockIdx.x * blockDim.x + threadIdx.x;
    if (e >= n_edges) return;
    int2 uv = edges[e];
    float p = phases[e];
    float s = __sinf(p), c = __cosf(p);
    float2 hu = x2[uv.x], hv = x2[uv.y];
    unsafeAtomicAdd(&out[2 * uv.y + 0], hu.x * c - hu.y * s);
    unsafeAtomicAdd(&out[2 * uv.y + 1], hu.x * s + hu.y * c);
    unsafeAtomicAdd(&out[2 * uv.x + 0], hv.x * c + hv.y * s);
    unsafeAtomicAdd(&out[2 * uv.x + 1], hv.y * c - hv.x * s);
}

// -----------------------------------------------------------------------------

extern "C" void kernel_launch(void* const* d_in, const int* in_sizes, int n_in,
                              void* d_out, int out_size, void* d_ws, size_t ws_size,
                              hipStream_t stream) {
    const float* x      = (const float*)d_in[0];
    const float* phases = (const float*)d_in[1];
    const int2*  edges  = (const int2*)d_in[2];
    float* out = (float*)d_out;

    const int n_nodes = out_size / 2;
    const int E       = in_sizes[1];
    const int nb      = (n_nodes + BUCKET_NODES - 1) >> NODE_SHIFT;

    // Pick smallest chunk count k whose records + cursors + xh table fit in ws.
    int chosen_k = 0, chosen_cap = 0;
    if (d_ws && nb <= MAX_NB) {
        const int ks[5] = {1, 2, 4, 8, 16};
        for (int i = 0; i < 5; ++i) {
            int k = ks[i];
            long long e_chunk = ((long long)E + k - 1) / k;
            double m = (double)(2 * e_chunk) / (double)nb;
            long long cap = (long long)(m + 10.0 * sqrt(m) + 64.0);
            cap = (cap + 255) & ~255LL;
            long long need = (long long)nb * cap * 8
                           + (((long long)nb * 4 + 255) & ~255LL)
                           + (long long)n_nodes * 4 + 512;
            if ((size_t)need <= ws_size) { chosen_k = k; chosen_cap = (int)cap; break; }
        }
    }

    if (chosen_k == 0) {
        rot_init_out<<<(out_size + 255) / 256, 256, 0, stream>>>(x, out, out_size);
        rot_edge_atomic<<<(E + 255) / 256, 256, 0, stream>>>(
            (const float2*)x, phases, edges, out, E);
        return;
    }

    const int cap = chosen_cap;
    uint2*   records = (uint2*)d_ws;
    size_t   off = (size_t)nb * cap * 8;
    uint*    cursors = (uint*)((char*)d_ws + off);
    off += ((size_t)nb * 4 + 255) & ~(size_t)255;
    __half2* xh = (__half2*)((char*)d_ws + off);

    // Build the 4 MB half2 gather table (fits per-XCD L2).
    rot_make_xh<<<(n_nodes + 255) / 256, 256, 0, stream>>>((const float2*)x, xh, n_nodes);

    const int e_chunk = (E + chosen_k - 1) / chosen_k;
    for (int cidx = 0; cidx < chosen_k; ++cidx) {
        int e0 = cidx * e_chunk;
        int e1 = (e0 + e_chunk < E) ? (e0 + e_chunk) : E;
        if (e0 >= e1) break;

        rot_zero_cursors<<<(nb + 255) / 256, 256, 0, stream>>>(cursors, nb);

        int nblk = (e1 - e0 + EPB - 1) / EPB;
        rot_partition<<<nblk, PART_BLOCK, 0, stream>>>(
            xh, phases, edges, cursors, records, e0, e1, cap, nb);

        rot_accumulate<<<nb, ACC_BLOCK, 0, stream>>>(
            (const float2*)x, cursors, records, (float2*)out, cap, n_nodes,
            cidx == 0 ? 1 : 0);
    }
}